// Round 1
// baseline (515.206 us; speedup 1.0000x reference)
//
#include <hip/hip_runtime.h>
#include <hip/hip_bf16.h>
#include <stdint.h>

typedef __attribute__((ext_vector_type(8))) short short8;
typedef __attribute__((ext_vector_type(4))) float f32x4;

#define B_ 2
#define N1 2048
#define N2 256
#define NT 2304
#define D_ 1024
#define H_ 16
#define HD 64

static __device__ __forceinline__ float bf2f(short s){
  union { unsigned int u; float f; } u;
  u.u = ((unsigned int)(unsigned short)s) << 16;
  return u.f;
}
// round-to-nearest-even f32 -> bf16 (finite inputs)
static __device__ __forceinline__ short f2bf(float f){
  union { float f; unsigned int u; } v; v.f = f;
  unsigned int u = v.u;
  unsigned int lsb = (u >> 16) & 1u;
  u += 0x7fffu + lsb;
  return (short)(u >> 16);
}

static __device__ __forceinline__ void gload16(const void* g, void* l){
  __builtin_amdgcn_global_load_lds(
      (const __attribute__((address_space(1))) void*)g,
      (__attribute__((address_space(3))) void*)l, 16, 0, 0);
}

// ---------------- fp32 -> bf16 convert ----------------
__global__ __launch_bounds__(256) void k_cvt_bf16(const float* __restrict__ in,
                                                  short* __restrict__ out, int n){
  int i = (blockIdx.x * 256 + threadIdx.x) * 8;
  if (i >= n) return;
  float4 a = *(const float4*)(in + i);
  float4 b = *(const float4*)(in + i + 4);
  short8 o;
  o[0]=f2bf(a.x); o[1]=f2bf(a.y); o[2]=f2bf(a.z); o[3]=f2bf(a.w);
  o[4]=f2bf(b.x); o[5]=f2bf(b.y); o[6]=f2bf(b.z); o[7]=f2bf(b.w);
  *(short8*)(out + i) = o;
}

// ---------------- W (K x N, f32) -> Wt (N x K, bf16) ----------------
__global__ __launch_bounds__(256) void k_transpose_w(const float* __restrict__ W,
                                                     short* __restrict__ Wt,
                                                     int K, int N){
  __shared__ float tl[64][65];
  const int n0 = blockIdx.x * 64, k0 = blockIdx.y * 64;
  const int t = threadIdx.x, r = t >> 2, c = (t & 3) * 16;
  const float* src = W + (size_t)(k0 + r) * N + n0 + c;
  #pragma unroll
  for (int i = 0; i < 16; i += 4){
    float4 v = *(const float4*)(src + i);
    tl[r][c+i] = v.x; tl[r][c+i+1] = v.y; tl[r][c+i+2] = v.z; tl[r][c+i+3] = v.w;
  }
  __syncthreads();
  short8 o0, o1;
  #pragma unroll
  for (int i = 0; i < 8; i++) o0[i] = f2bf(tl[c+i][r]);
  #pragma unroll
  for (int i = 0; i < 8; i++) o1[i] = f2bf(tl[c+8+i][r]);
  short* dst = Wt + (size_t)(n0 + r) * K + k0 + c;
  *(short8*)(dst)     = o0;
  *(short8*)(dst + 8) = o1;
}

// ---------------- GEMM: C[M,N] = A[M,K] * Bt[N,K]^T + bias ----------------
// m97-style: 128x128 tile, BK=32, 4 waves (2x2), global_load_lds w16.
template<int OUT_BF16>
__global__ __launch_bounds__(256) void k_gemm_bt(const short* __restrict__ A,
                                                 const short* __restrict__ Bt,
                                                 const float* __restrict__ bias,
                                                 void* __restrict__ Cp,
                                                 int M, int N, int K){
  __shared__ __align__(16) short As[128*32];
  __shared__ __align__(16) short Bs[128*32];
  const int t = threadIdx.x;
  const int w = t >> 6, l = t & 63;
  const int lc = l & 15, g = l >> 4;
  const int tm = blockIdx.y * 128, tn = blockIdx.x * 128;
  const int wm = (w >> 1) * 64, wn = (w & 1) * 64;

  const int r0 = w*32 + (l >> 2);
  const int r1 = r0 + 16;
  const int cb = (l & 3) * 16; // byte offset within 64B row

  const char* Ag0 = (const char*)(A + (size_t)(tm + r0) * K) + cb;
  const char* Ag1 = (const char*)(A + (size_t)(tm + r1) * K) + cb;
  const char* Bg0 = (const char*)(Bt + (size_t)(tn + r0) * K) + cb;
  const char* Bg1 = (const char*)(Bt + (size_t)(tn + r1) * K) + cb;
  char* Al0 = (char*)As + (w*2  )*1024;
  char* Al1 = (char*)As + (w*2+1)*1024;
  char* Bl0 = (char*)Bs + (w*2  )*1024;
  char* Bl1 = (char*)Bs + (w*2+1)*1024;

  f32x4 acc[4][4];
  #pragma unroll
  for (int m=0;m<4;m++){
    #pragma unroll
    for (int n=0;n<4;n++){ acc[m][n][0]=0.f; acc[m][n][1]=0.f; acc[m][n][2]=0.f; acc[m][n][3]=0.f; }
  }

  for (int k0 = 0; k0 < K; k0 += 32){
    const int kb = k0 * 2;
    gload16(Ag0 + kb, Al0);
    gload16(Ag1 + kb, Al1);
    gload16(Bg0 + kb, Bl0);
    gload16(Bg1 + kb, Bl1);
    __syncthreads();
    short8 af[4], bfr[4];
    #pragma unroll
    for (int m=0;m<4;m++) af[m]  = *(const short8*)(As + (wm + m*16 + lc)*32 + g*8);
    #pragma unroll
    for (int n=0;n<4;n++) bfr[n] = *(const short8*)(Bs + (wn + n*16 + lc)*32 + g*8);
    #pragma unroll
    for (int m=0;m<4;m++){
      #pragma unroll
      for (int n=0;n<4;n++)
        acc[m][n] = __builtin_amdgcn_mfma_f32_16x16x32_bf16(af[m], bfr[n], acc[m][n], 0, 0, 0);
    }
    __syncthreads();
  }

  #pragma unroll
  for (int n=0;n<4;n++){
    const int col = tn + wn + n*16 + lc;
    const float bv = bias[col];
    #pragma unroll
    for (int m=0;m<4;m++){
      const int row = tm + wm + m*16 + g*4;
      #pragma unroll
      for (int r=0;r<4;r++){
        float v = acc[m][n][r] + bv;
        if (OUT_BF16) ((short*)Cp)[(size_t)(row + r)*N + col] = f2bf(v);
        else          ((float*)Cp)[(size_t)(row + r)*N + col] = v;
      }
    }
  }
}

// ---------------- per-head LN (+ optional RoPE), split QKV ----------------
__global__ __launch_bounds__(256) void k_lnrope(const short* __restrict__ qkv,
    const float* __restrict__ qw, const float* __restrict__ qb,
    const float* __restrict__ kw, const float* __restrict__ kb,
    const float* __restrict__ fcos, const float* __restrict__ fsin,
    short* __restrict__ Qo, short* __restrict__ Ko, short* __restrict__ Vo,
    int Nseq, int posoff, int use_rope){
  const int wv = (blockIdx.x * 256 + threadIdx.x) >> 6;
  const int l = threadIdx.x & 63;
  const int h = wv % H_;
  const int n = (wv / H_) % Nseq;
  const int b = wv / (H_ * Nseq);
  const size_t ibase = ((size_t)(b * Nseq + n)) * 3072 + h * 64 + l;
  float q = bf2f(qkv[ibase]);
  float k = bf2f(qkv[ibase + 1024]);
  short v = qkv[ibase + 2048];

  float mu = q;
  #pragma unroll
  for (int mk = 1; mk < 64; mk <<= 1) mu += __shfl_xor(mu, mk, 64);
  mu *= (1.f/64.f);
  float dq = q - mu;
  float var = dq * dq;
  #pragma unroll
  for (int mk = 1; mk < 64; mk <<= 1) var += __shfl_xor(var, mk, 64);
  var *= (1.f/64.f);
  float qn = dq * rsqrtf(var + 1e-5f) * qw[l] + qb[l];

  float muk = k;
  #pragma unroll
  for (int mk = 1; mk < 64; mk <<= 1) muk += __shfl_xor(muk, mk, 64);
  muk *= (1.f/64.f);
  float dk = k - muk;
  float vark = dk * dk;
  #pragma unroll
  for (int mk = 1; mk < 64; mk <<= 1) vark += __shfl_xor(vark, mk, 64);
  vark *= (1.f/64.f);
  float kn = dk * rsqrtf(vark + 1e-5f) * kw[l] + kb[l];

  if (use_rope){
    float cv = fcos[(size_t)n * 32 + (l >> 1)];
    float sv = fsin[(size_t)n * 32 + (l >> 1)];
    float qp = __shfl_xor(qn, 1, 64);
    float kp = __shfl_xor(kn, 1, 64);
    qn = (l & 1) ? (qp * sv + qn * cv) : (qn * cv - qp * sv);
    kn = (l & 1) ? (kp * sv + kn * cv) : (kn * cv - kp * sv);
  }
  const size_t obase = ((size_t)(b * H_ + h) * NT + posoff + n) * HD + l;
  Qo[obase] = f2bf(qn);
  Ko[obase] = f2bf(kn);
  Vo[obase] = v;
}

// ---------------- V (B,H,NT,64) -> Vt (B,H,64,NT) ----------------
__global__ __launch_bounds__(256) void k_transpose_v(const short* __restrict__ V,
                                                     short* __restrict__ Vt){
  __shared__ short tl[64][72];
  const int blk = blockIdx.x;
  const int bh = blk / 36;
  const int n0 = (blk % 36) * 64;
  const int t = threadIdx.x, r = t >> 2, c = (t & 3) * 16;
  const short* src = V + ((size_t)bh * NT + n0 + r) * HD + c;
  short8 v0 = *(const short8*)(src);
  short8 v1 = *(const short8*)(src + 8);
  #pragma unroll
  for (int i=0;i<8;i++){ tl[r][c+i] = v0[i]; tl[r][c+8+i] = v1[i]; }
  __syncthreads();
  short8 o0, o1;
  #pragma unroll
  for (int i=0;i<8;i++){ o0[i] = tl[c+i][r]; o1[i] = tl[c+8+i][r]; }
  short* dst = Vt + ((size_t)bh * HD + r) * NT + n0 + c;
  *(short8*)dst       = o0;
  *(short8*)(dst + 8) = o1;
}

// ---------------- flash attention, full (unmasked) softmax over NT keys ----
// block = 4 waves; wave w owns 16 q-rows; KV tile = 64.
__global__ __launch_bounds__(256) void k_attn(const short* __restrict__ Q,
                                              const short* __restrict__ Kg,
                                              const short* __restrict__ Vt,
                                              short* __restrict__ o1,
                                              short* __restrict__ o2){
  __shared__ __align__(16) short Ps[64][72];
  const int t = threadIdx.x, w = t >> 6, l = t & 63;
  const int lc = l & 15, g = l >> 4;
  const int blk = blockIdx.x;
  const int bh = blk / 36, qt = blk % 36;
  const int b = bh >> 4, h = bh & 15;
  const int q0 = qt * 64;
  const short* Qb = Q  + (size_t)bh * NT * HD;
  const short* Kb = Kg + (size_t)bh * NT * HD;
  const short* Vb = Vt + (size_t)bh * HD * NT;

  short8 qf0 = *(const short8*)(Qb + (size_t)(q0 + w*16 + lc) * HD + g*8);
  short8 qf1 = *(const short8*)(Qb + (size_t)(q0 + w*16 + lc) * HD + g*8 + 32);

  float m[4], lsum[4];
  f32x4 oacc[4];
  #pragma unroll
  for (int r=0;r<4;r++){ m[r] = -1e30f; lsum[r] = 0.f; }
  #pragma unroll
  for (int j=0;j<4;j++){ oacc[j][0]=0.f; oacc[j][1]=0.f; oacc[j][2]=0.f; oacc[j][3]=0.f; }

  const float scale = 0.125f; // hd^-0.5

  for (int kv0 = 0; kv0 < NT; kv0 += 64){
    f32x4 s[4];
    #pragma unroll
    for (int j=0;j<4;j++){
      const short* kp = Kb + (size_t)(kv0 + j*16 + lc) * HD + g*8;
      short8 b0 = *(const short8*)(kp);
      short8 b1 = *(const short8*)(kp + 32);
      f32x4 a; a[0]=0.f; a[1]=0.f; a[2]=0.f; a[3]=0.f;
      a = __builtin_amdgcn_mfma_f32_16x16x32_bf16(qf0, b0, a, 0, 0, 0);
      a = __builtin_amdgcn_mfma_f32_16x16x32_bf16(qf1, b1, a, 0, 0, 0);
      s[j] = a;
    }
    float p[4][4];
    #pragma unroll
    for (int r=0;r<4;r++){
      float v = fmaxf(fmaxf(s[0][r], s[1][r]), fmaxf(s[2][r], s[3][r]));
      v = fmaxf(v, __shfl_xor(v, 1, 64));
      v = fmaxf(v, __shfl_xor(v, 2, 64));
      v = fmaxf(v, __shfl_xor(v, 4, 64));
      v = fmaxf(v, __shfl_xor(v, 8, 64));
      float mn = fmaxf(m[r], v * scale);
      float f = __expf(m[r] - mn);
      m[r] = mn;
      float rs = 0.f;
      #pragma unroll
      for (int j=0;j<4;j++){
        float pv = __expf(s[j][r] * scale - mn);
        p[j][r] = pv;
        rs += pv;
      }
      rs += __shfl_xor(rs, 1, 64);
      rs += __shfl_xor(rs, 2, 64);
      rs += __shfl_xor(rs, 4, 64);
      rs += __shfl_xor(rs, 8, 64);
      lsum[r] = lsum[r] * f + rs;
      #pragma unroll
      for (int j=0;j<4;j++) oacc[j][r] *= f;
    }
    // P -> LDS (wave-private rows; same-wave DS ordering, no barrier needed)
    #pragma unroll
    for (int j=0;j<4;j++){
      #pragma unroll
      for (int r=0;r<4;r++)
        Ps[w*16 + g*4 + r][lc + 16*j] = f2bf(p[j][r]);
    }
    #pragma unroll
    for (int kk=0;kk<2;kk++){
      short8 pa = *(const short8*)(&Ps[w*16 + lc][kk*32 + g*8]);
      #pragma unroll
      for (int j=0;j<4;j++){
        short8 vb = *(const short8*)(Vb + (size_t)(lc + 16*j) * NT + kv0 + kk*32 + g*8);
        oacc[j] = __builtin_amdgcn_mfma_f32_16x16x32_bf16(pa, vb, oacc[j], 0, 0, 0);
      }
    }
  }

  #pragma unroll
  for (int j=0;j<4;j++){
    #pragma unroll
    for (int r=0;r<4;r++){
      const int qi = q0 + w*16 + g*4 + r;
      float ov = oacc[j][r] / lsum[r];
      short obf = f2bf(ov);
      const int col = h*64 + lc + 16*j;
      if (qi < N1) o1[((size_t)b * N1 + qi) * D_ + col] = obf;
      else         o2[((size_t)b * N2 + (qi - N1)) * D_ + col] = obf;
    }
  }
}

extern "C" void kernel_launch(void* const* d_in, const int* in_sizes, int n_in,
                              void* d_out, int out_size, void* d_ws, size_t ws_size,
                              hipStream_t stream){
  const float* x    = (const float*)d_in[0];
  const float* c    = (const float*)d_in[1];
  const float* fc   = (const float*)d_in[2];
  const float* fs   = (const float*)d_in[3];
  const float* Wq1  = (const float*)d_in[4];
  const float* bq1  = (const float*)d_in[5];
  const float* Wq2  = (const float*)d_in[6];
  const float* bq2  = (const float*)d_in[7];
  const float* qn1w = (const float*)d_in[8];
  const float* qn1b = (const float*)d_in[9];
  const float* kn1w = (const float*)d_in[10];
  const float* kn1b = (const float*)d_in[11];
  const float* qn2w = (const float*)d_in[12];
  const float* qn2b = (const float*)d_in[13];
  const float* kn2w = (const float*)d_in[14];
  const float* kn2b = (const float*)d_in[15];
  const float* Wp1  = (const float*)d_in[16];
  const float* bp1  = (const float*)d_in[17];
  const float* Wp2  = (const float*)d_in[18];
  const float* bp2  = (const float*)d_in[19];
  float* out = (float*)d_out;

  char* ws = (char*)d_ws;
  short* xb   = (short*)(ws);                       // 8,388,608
  short* cb   = (short*)(ws + 8388608);             // 1,048,576
  short* Wt1  = (short*)(ws + 9437184);             // 6,291,456
  short* Wt2  = (short*)(ws + 15728640);            // 6,291,456
  short* Wtp1 = (short*)(ws + 22020096);            // 2,097,152
  short* Wtp2 = (short*)(ws + 24117248);            // 2,097,152
  short* qkv1 = (short*)(ws + 26214400);            // 25,165,824 (bf16 4096x3072)
  short* qkv2 = (short*)(ws + 51380224);            // 3,145,728
  short* Qb   = (short*)(ws + 54525952);            // 9,437,184
  short* Kb   = (short*)(ws + 63963136);            // 9,437,184
  short* Vb   = (short*)(ws + 73400320);            // 9,437,184  -> total 82,837,504
  // aliases into qkv1 region (qkv1 fully consumed by k_lnrope before these are written)
  short* o1   = (short*)(ws + 26214400);            // 8,388,608
  short* o2   = (short*)(ws + 26214400 + 8388608);  // 1,048,576
  short* Vtb  = (short*)(ws + 26214400 + 9437184);  // 9,437,184

  k_cvt_bf16<<<2048, 256, 0, stream>>>(x, xb, 4194304);
  k_cvt_bf16<<<256, 256, 0, stream>>>(c, cb, 524288);
  k_transpose_w<<<dim3(48,16), 256, 0, stream>>>(Wq1, Wt1, 1024, 3072);
  k_transpose_w<<<dim3(48,16), 256, 0, stream>>>(Wq2, Wt2, 1024, 3072);
  k_transpose_w<<<dim3(16,16), 256, 0, stream>>>(Wp1, Wtp1, 1024, 1024);
  k_transpose_w<<<dim3(16,16), 256, 0, stream>>>(Wp2, Wtp2, 1024, 1024);

  k_gemm_bt<1><<<dim3(24,32), 256, 0, stream>>>(xb, Wt1, bq1, qkv1, 4096, 3072, 1024);
  k_gemm_bt<1><<<dim3(24,4),  256, 0, stream>>>(cb, Wt2, bq2, qkv2,  512, 3072, 1024);

  k_lnrope<<<16384, 256, 0, stream>>>(qkv1, qn1w, qn1b, kn1w, kn1b, fc, fs, Qb, Kb, Vb, 2048, 0, 1);
  k_lnrope<<<2048,  256, 0, stream>>>(qkv2, qn2w, qn2b, kn2w, kn2b, fc, fs, Qb, Kb, Vb,  256, 2048, 0);

  k_transpose_v<<<1152, 256, 0, stream>>>(Vb, Vtb);
  k_attn<<<1152, 256, 0, stream>>>(Qb, Kb, Vtb, o1, o2);

  k_gemm_bt<0><<<dim3(8,32), 256, 0, stream>>>(o1, Wtp1, bp1, out,           4096, 1024, 1024);
  k_gemm_bt<0><<<dim3(8,4),  256, 0, stream>>>(o2, Wtp2, bp2, out + 4194304,  512, 1024, 1024);
}

// Round 2
// 499.360 us; speedup vs baseline: 1.0317x; 1.0317x over previous
//
#include <hip/hip_runtime.h>
#include <hip/hip_bf16.h>
#include <stdint.h>

typedef __attribute__((ext_vector_type(8))) short short8;
typedef __attribute__((ext_vector_type(4))) float f32x4;

#define B_ 2
#define N1 2048
#define N2 256
#define NT 2304
#define D_ 1024
#define H_ 16
#define HD 64
// attention scale folded into Q: hd^-0.5 * log2(e)
#define QSCALE 0.18033688011112042f

static __device__ __forceinline__ float bf2f(short s){
  union { unsigned int u; float f; } u;
  u.u = ((unsigned int)(unsigned short)s) << 16;
  return u.f;
}
// round-to-nearest-even f32 -> bf16 (finite inputs)
static __device__ __forceinline__ short f2bf(float f){
  union { float f; unsigned int u; } v; v.f = f;
  unsigned int u = v.u;
  unsigned int lsb = (u >> 16) & 1u;
  u += 0x7fffu + lsb;
  return (short)(u >> 16);
}

static __device__ __forceinline__ float fexp2(float x){
#if __has_builtin(__builtin_amdgcn_exp2f)
  return __builtin_amdgcn_exp2f(x);
#else
  return exp2f(x);
#endif
}

static __device__ __forceinline__ void gload16(const void* g, void* l){
  __builtin_amdgcn_global_load_lds(
      (const __attribute__((address_space(1))) void*)g,
      (__attribute__((address_space(3))) void*)l, 16, 0, 0);
}

// ---------------- fp32 -> bf16 convert ----------------
__global__ __launch_bounds__(256) void k_cvt_bf16(const float* __restrict__ in,
                                                  short* __restrict__ out, int n){
  int i = (blockIdx.x * 256 + threadIdx.x) * 8;
  if (i >= n) return;
  float4 a = *(const float4*)(in + i);
  float4 b = *(const float4*)(in + i + 4);
  short8 o;
  o[0]=f2bf(a.x); o[1]=f2bf(a.y); o[2]=f2bf(a.z); o[3]=f2bf(a.w);
  o[4]=f2bf(b.x); o[5]=f2bf(b.y); o[6]=f2bf(b.z); o[7]=f2bf(b.w);
  *(short8*)(out + i) = o;
}

// ---------------- W (K x N, f32) -> Wt (N x K, bf16) ----------------
__global__ __launch_bounds__(256) void k_transpose_w(const float* __restrict__ W,
                                                     short* __restrict__ Wt,
                                                     int K, int N){
  __shared__ float tl[64][65];
  const int n0 = blockIdx.x * 64, k0 = blockIdx.y * 64;
  const int t = threadIdx.x, r = t >> 2, c = (t & 3) * 16;
  const float* src = W + (size_t)(k0 + r) * N + n0 + c;
  #pragma unroll
  for (int i = 0; i < 16; i += 4){
    float4 v = *(const float4*)(src + i);
    tl[r][c+i] = v.x; tl[r][c+i+1] = v.y; tl[r][c+i+2] = v.z; tl[r][c+i+3] = v.w;
  }
  __syncthreads();
  short8 o0, o1;
  #pragma unroll
  for (int i = 0; i < 8; i++) o0[i] = f2bf(tl[c+i][r]);
  #pragma unroll
  for (int i = 0; i < 8; i++) o1[i] = f2bf(tl[c+8+i][r]);
  short* dst = Wt + (size_t)(n0 + r) * K + k0 + c;
  *(short8*)(dst)     = o0;
  *(short8*)(dst + 8) = o1;
}

// ---------------- GEMM: C[M,N] = A[M,K] * Bt[N,K]^T + bias ----------------
// m97-style: 128x128 tile, BK=32, 4 waves (2x2), global_load_lds w16.
template<int OUT_BF16>
__global__ __launch_bounds__(256) void k_gemm_bt(const short* __restrict__ A,
                                                 const short* __restrict__ Bt,
                                                 const float* __restrict__ bias,
                                                 void* __restrict__ Cp,
                                                 int M, int N, int K){
  __shared__ __align__(16) short As[128*32];
  __shared__ __align__(16) short Bs[128*32];
  const int t = threadIdx.x;
  const int w = t >> 6, l = t & 63;
  const int lc = l & 15, g = l >> 4;
  const int tm = blockIdx.y * 128, tn = blockIdx.x * 128;
  const int wm = (w >> 1) * 64, wn = (w & 1) * 64;

  const int r0 = w*32 + (l >> 2);
  const int r1 = r0 + 16;
  const int cb = (l & 3) * 16; // byte offset within 64B row

  const char* Ag0 = (const char*)(A + (size_t)(tm + r0) * K) + cb;
  const char* Ag1 = (const char*)(A + (size_t)(tm + r1) * K) + cb;
  const char* Bg0 = (const char*)(Bt + (size_t)(tn + r0) * K) + cb;
  const char* Bg1 = (const char*)(Bt + (size_t)(tn + r1) * K) + cb;
  char* Al0 = (char*)As + (w*2  )*1024;
  char* Al1 = (char*)As + (w*2+1)*1024;
  char* Bl0 = (char*)Bs + (w*2  )*1024;
  char* Bl1 = (char*)Bs + (w*2+1)*1024;

  f32x4 acc[4][4];
  #pragma unroll
  for (int m=0;m<4;m++){
    #pragma unroll
    for (int n=0;n<4;n++){ acc[m][n][0]=0.f; acc[m][n][1]=0.f; acc[m][n][2]=0.f; acc[m][n][3]=0.f; }
  }

  for (int k0 = 0; k0 < K; k0 += 32){
    const int kb = k0 * 2;
    gload16(Ag0 + kb, Al0);
    gload16(Ag1 + kb, Al1);
    gload16(Bg0 + kb, Bl0);
    gload16(Bg1 + kb, Bl1);
    __syncthreads();
    short8 af[4], bfr[4];
    #pragma unroll
    for (int m=0;m<4;m++) af[m]  = *(const short8*)(As + (wm + m*16 + lc)*32 + g*8);
    #pragma unroll
    for (int n=0;n<4;n++) bfr[n] = *(const short8*)(Bs + (wn + n*16 + lc)*32 + g*8);
    #pragma unroll
    for (int m=0;m<4;m++){
      #pragma unroll
      for (int n=0;n<4;n++)
        acc[m][n] = __builtin_amdgcn_mfma_f32_16x16x32_bf16(af[m], bfr[n], acc[m][n], 0, 0, 0);
    }
    __syncthreads();
  }

  #pragma unroll
  for (int n=0;n<4;n++){
    const int col = tn + wn + n*16 + lc;
    const float bv = bias[col];
    #pragma unroll
    for (int m=0;m<4;m++){
      const int row = tm + wm + m*16 + g*4;
      #pragma unroll
      for (int r=0;r<4;r++){
        float v = acc[m][n][r] + bv;
        if (OUT_BF16) ((short*)Cp)[(size_t)(row + r)*N + col] = f2bf(v);
        else          ((float*)Cp)[(size_t)(row + r)*N + col] = v;
      }
    }
  }
}

// ---------------- per-head LN (+ optional RoPE), split QKV ----------------
// Q gets QSCALE (= hd^-0.5 * log2e) folded in; attention works in exp2 domain.
__global__ __launch_bounds__(256) void k_lnrope(const short* __restrict__ qkv,
    const float* __restrict__ qw, const float* __restrict__ qb,
    const float* __restrict__ kw, const float* __restrict__ kb,
    const float* __restrict__ fcos, const float* __restrict__ fsin,
    short* __restrict__ Qo, short* __restrict__ Ko, short* __restrict__ Vo,
    int Nseq, int posoff, int use_rope){
  const int wv = (blockIdx.x * 256 + threadIdx.x) >> 6;
  const int l = threadIdx.x & 63;
  const int h = wv % H_;
  const int n = (wv / H_) % Nseq;
  const int b = wv / (H_ * Nseq);
  const size_t ibase = ((size_t)(b * Nseq + n)) * 3072 + h * 64 + l;
  float q = bf2f(qkv[ibase]);
  float k = bf2f(qkv[ibase + 1024]);
  short v = qkv[ibase + 2048];

  float mu = q;
  #pragma unroll
  for (int mk = 1; mk < 64; mk <<= 1) mu += __shfl_xor(mu, mk, 64);
  mu *= (1.f/64.f);
  float dq = q - mu;
  float var = dq * dq;
  #pragma unroll
  for (int mk = 1; mk < 64; mk <<= 1) var += __shfl_xor(var, mk, 64);
  var *= (1.f/64.f);
  float qn = dq * rsqrtf(var + 1e-5f) * qw[l] + qb[l];

  float muk = k;
  #pragma unroll
  for (int mk = 1; mk < 64; mk <<= 1) muk += __shfl_xor(muk, mk, 64);
  muk *= (1.f/64.f);
  float dk = k - muk;
  float vark = dk * dk;
  #pragma unroll
  for (int mk = 1; mk < 64; mk <<= 1) vark += __shfl_xor(vark, mk, 64);
  vark *= (1.f/64.f);
  float kn = dk * rsqrtf(vark + 1e-5f) * kw[l] + kb[l];

  if (use_rope){
    float cv = fcos[(size_t)n * 32 + (l >> 1)];
    float sv = fsin[(size_t)n * 32 + (l >> 1)];
    float qp = __shfl_xor(qn, 1, 64);
    float kp = __shfl_xor(kn, 1, 64);
    qn = (l & 1) ? (qp * sv + qn * cv) : (qn * cv - qp * sv);
    kn = (l & 1) ? (kp * sv + kn * cv) : (kn * cv - kp * sv);
  }
  qn *= QSCALE;
  const size_t obase = ((size_t)(b * H_ + h) * NT + posoff + n) * HD + l;
  Qo[obase] = f2bf(qn);
  Ko[obase] = f2bf(kn);
  Vo[obase] = v;
}

// ---------------- V (B,H,NT,64) -> Vt (B,H,64,NT) ----------------
__global__ __launch_bounds__(256) void k_transpose_v(const short* __restrict__ V,
                                                     short* __restrict__ Vt){
  __shared__ short tl[64][72];
  const int blk = blockIdx.x;
  const int bh = blk / 36;
  const int n0 = (blk % 36) * 64;
  const int t = threadIdx.x, r = t >> 2, c = (t & 3) * 16;
  const short* src = V + ((size_t)bh * NT + n0 + r) * HD + c;
  short8 v0 = *(const short8*)(src);
  short8 v1 = *(const short8*)(src + 8);
  #pragma unroll
  for (int i=0;i<8;i++){ tl[r][c+i] = v0[i]; tl[r][c+8+i] = v1[i]; }
  __syncthreads();
  short8 o0, o1;
  #pragma unroll
  for (int i=0;i<8;i++){ o0[i] = tl[c+i][r]; o1[i] = tl[c+8+i][r]; }
  short* dst = Vt + ((size_t)bh * HD + r) * NT + n0 + c;
  *(short8*)dst       = o0;
  *(short8*)(dst + 8) = o1;
}

// ---------------- flash attention, KV-split-2 + online-softmax merge -------
// block = 4 waves over 32 q-rows: wave w: q-sub (w&1)*16, KV half (w>>1).
// Each wave: 16 q-rows x 18 KV tiles of 64. Merge halves via LDS at end.
__global__ __launch_bounds__(256) void k_attn(const short* __restrict__ Q,
                                              const short* __restrict__ Kg,
                                              const short* __restrict__ Vt,
                                              short* __restrict__ o1,
                                              short* __restrict__ o2){
  __shared__ __align__(16) short Ps[4][16][72];
  __shared__ __align__(16) float Om[2][16][64];
  __shared__ float Ms[2][16], Ls[2][16];
  const int t = threadIdx.x, w = t >> 6, l = t & 63;
  const int lc = l & 15, g = l >> 4;
  const int h = w >> 1, qsub = w & 1;
  const int blk = blockIdx.x;
  const int bh = blk / 72, qt = blk % 72;
  const int b = bh >> 4, hh = bh & 15;
  const int q0 = qt * 32 + qsub * 16;
  const short* Qb = Q  + (size_t)bh * NT * HD;
  const short* Kb = Kg + (size_t)bh * NT * HD;
  const short* Vb = Vt + (size_t)bh * HD * NT;

  short8 qf0 = *(const short8*)(Qb + (size_t)(q0 + lc) * HD + g*8);
  short8 qf1 = *(const short8*)(Qb + (size_t)(q0 + lc) * HD + g*8 + 32);

  float m[4], lsum[4];
  f32x4 oacc[4];
  #pragma unroll
  for (int r=0;r<4;r++){ m[r] = -1e30f; lsum[r] = 0.f; }
  #pragma unroll
  for (int j=0;j<4;j++){ oacc[j][0]=0.f; oacc[j][1]=0.f; oacc[j][2]=0.f; oacc[j][3]=0.f; }

  for (int ti = 0; ti < 18; ++ti){
    const int kv0 = (h * 18 + ti) * 64;
    f32x4 s[4];
    #pragma unroll
    for (int j=0;j<4;j++){
      const short* kp = Kb + (size_t)(kv0 + j*16 + lc) * HD + g*8;
      short8 b0 = *(const short8*)(kp);
      short8 b1 = *(const short8*)(kp + 32);
      f32x4 a; a[0]=0.f; a[1]=0.f; a[2]=0.f; a[3]=0.f;
      a = __builtin_amdgcn_mfma_f32_16x16x32_bf16(qf0, b0, a, 0, 0, 0);
      a = __builtin_amdgcn_mfma_f32_16x16x32_bf16(qf1, b1, a, 0, 0, 0);
      s[j] = a;
    }
    float p[4][4];
    #pragma unroll
    for (int r=0;r<4;r++){
      float v = fmaxf(fmaxf(s[0][r], s[1][r]), fmaxf(s[2][r], s[3][r]));
      v = fmaxf(v, __shfl_xor(v, 1, 64));
      v = fmaxf(v, __shfl_xor(v, 2, 64));
      v = fmaxf(v, __shfl_xor(v, 4, 64));
      v = fmaxf(v, __shfl_xor(v, 8, 64));
      float mn = fmaxf(m[r], v);
      float f = fexp2(m[r] - mn);
      m[r] = mn;
      float rs = 0.f;
      #pragma unroll
      for (int j=0;j<4;j++){
        float pv = fexp2(s[j][r] - mn);
        p[j][r] = pv;
        rs += pv;
      }
      rs += __shfl_xor(rs, 1, 64);
      rs += __shfl_xor(rs, 2, 64);
      rs += __shfl_xor(rs, 4, 64);
      rs += __shfl_xor(rs, 8, 64);
      lsum[r] = lsum[r] * f + rs;
      #pragma unroll
      for (int j=0;j<4;j++) oacc[j][r] *= f;
    }
    // P -> LDS (wave-private rows; same-wave DS ordering, no barrier needed)
    #pragma unroll
    for (int j=0;j<4;j++){
      #pragma unroll
      for (int r=0;r<4;r++)
        Ps[w][g*4 + r][lc + 16*j] = f2bf(p[j][r]);
    }
    #pragma unroll
    for (int kk=0;kk<2;kk++){
      short8 pa = *(const short8*)(&Ps[w][lc][kk*32 + g*8]);
      #pragma unroll
      for (int j=0;j<4;j++){
        short8 vb = *(const short8*)(Vb + (size_t)(lc + 16*j) * NT + kv0 + kk*32 + g*8);
        oacc[j] = __builtin_amdgcn_mfma_f32_16x16x32_bf16(pa, vb, oacc[j], 0, 0, 0);
      }
    }
  }

  // ---- merge the two KV halves (waves h=1 publish, h=0 combine+write) ----
  if (h == 1){
    #pragma unroll
    for (int j=0;j<4;j++){
      #pragma unroll
      for (int r=0;r<4;r++)
        Om[qsub][g*4 + r][lc + 16*j] = oacc[j][r];
    }
    if (lc == 0){
      #pragma unroll
      for (int r=0;r<4;r++){ Ms[qsub][g*4 + r] = m[r]; Ls[qsub][g*4 + r] = lsum[r]; }
    }
  }
  __syncthreads();
  if (h == 0){
    #pragma unroll
    for (int r=0;r<4;r++){
      const int row = g*4 + r;
      const float m1 = Ms[qsub][row];
      const float l1v = Ls[qsub][row];
      const float M = fmaxf(m[r], m1);
      const float f0 = fexp2(m[r] - M);
      const float f1 = fexp2(m1 - M);
      const float inv = 1.0f / (lsum[r] * f0 + l1v * f1);
      const int qi = q0 + row;
      #pragma unroll
      for (int j=0;j<4;j++){
        const float o1v = Om[qsub][row][lc + 16*j];
        const float ov = (oacc[j][r] * f0 + o1v * f1) * inv;
        const short obf = f2bf(ov);
        const int col = hh*64 + lc + 16*j;
        if (qi < N1) o1[((size_t)b * N1 + qi) * D_ + col] = obf;
        else         o2[((size_t)b * N2 + (qi - N1)) * D_ + col] = obf;
      }
    }
  }
}

extern "C" void kernel_launch(void* const* d_in, const int* in_sizes, int n_in,
                              void* d_out, int out_size, void* d_ws, size_t ws_size,
                              hipStream_t stream){
  const float* x    = (const float*)d_in[0];
  const float* c    = (const float*)d_in[1];
  const float* fc   = (const float*)d_in[2];
  const float* fs   = (const float*)d_in[3];
  const float* Wq1  = (const float*)d_in[4];
  const float* bq1  = (const float*)d_in[5];
  const float* Wq2  = (const float*)d_in[6];
  const float* bq2  = (const float*)d_in[7];
  const float* qn1w = (const float*)d_in[8];
  const float* qn1b = (const float*)d_in[9];
  const float* kn1w = (const float*)d_in[10];
  const float* kn1b = (const float*)d_in[11];
  const float* qn2w = (const float*)d_in[12];
  const float* qn2b = (const float*)d_in[13];
  const float* kn2w = (const float*)d_in[14];
  const float* kn2b = (const float*)d_in[15];
  const float* Wp1  = (const float*)d_in[16];
  const float* bp1  = (const float*)d_in[17];
  const float* Wp2  = (const float*)d_in[18];
  const float* bp2  = (const float*)d_in[19];
  float* out = (float*)d_out;

  char* ws = (char*)d_ws;
  short* xb   = (short*)(ws);                       // 8,388,608
  short* cb   = (short*)(ws + 8388608);             // 1,048,576
  short* Wt1  = (short*)(ws + 9437184);             // 6,291,456
  short* Wt2  = (short*)(ws + 15728640);            // 6,291,456
  short* Wtp1 = (short*)(ws + 22020096);            // 2,097,152
  short* Wtp2 = (short*)(ws + 24117248);            // 2,097,152
  short* qkv1 = (short*)(ws + 26214400);            // 25,165,824 (bf16 4096x3072)
  short* qkv2 = (short*)(ws + 51380224);            // 3,145,728
  short* Qb   = (short*)(ws + 54525952);            // 9,437,184
  short* Kb   = (short*)(ws + 63963136);            // 9,437,184
  short* Vb   = (short*)(ws + 73400320);            // 9,437,184  -> total 82,837,504
  // aliases into qkv1 region (qkv1 fully consumed by k_lnrope before these are written)
  short* o1   = (short*)(ws + 26214400);            // 8,388,608
  short* o2   = (short*)(ws + 26214400 + 8388608);  // 1,048,576
  short* Vtb  = (short*)(ws + 26214400 + 9437184);  // 9,437,184

  k_cvt_bf16<<<2048, 256, 0, stream>>>(x, xb, 4194304);
  k_cvt_bf16<<<256, 256, 0, stream>>>(c, cb, 524288);
  k_transpose_w<<<dim3(48,16), 256, 0, stream>>>(Wq1, Wt1, 1024, 3072);
  k_transpose_w<<<dim3(48,16), 256, 0, stream>>>(Wq2, Wt2, 1024, 3072);
  k_transpose_w<<<dim3(16,16), 256, 0, stream>>>(Wp1, Wtp1, 1024, 1024);
  k_transpose_w<<<dim3(16,16), 256, 0, stream>>>(Wp2, Wtp2, 1024, 1024);

  k_gemm_bt<1><<<dim3(24,32), 256, 0, stream>>>(xb, Wt1, bq1, qkv1, 4096, 3072, 1024);
  k_gemm_bt<1><<<dim3(24,4),  256, 0, stream>>>(cb, Wt2, bq2, qkv2,  512, 3072, 1024);

  k_lnrope<<<16384, 256, 0, stream>>>(qkv1, qn1w, qn1b, kn1w, kn1b, fc, fs, Qb, Kb, Vb, 2048, 0, 1);
  k_lnrope<<<2048,  256, 0, stream>>>(qkv2, qn2w, qn2b, kn2w, kn2b, fc, fs, Qb, Kb, Vb,  256, 2048, 0);

  k_transpose_v<<<1152, 256, 0, stream>>>(Vb, Vtb);
  k_attn<<<2304, 256, 0, stream>>>(Qb, Kb, Vtb, o1, o2);

  k_gemm_bt<0><<<dim3(8,32), 256, 0, stream>>>(o1, Wtp1, bp1, out,           4096, 1024, 1024);
  k_gemm_bt<0><<<dim3(8,4),  256, 0, stream>>>(o2, Wtp2, bp2, out + 4194304,  512, 1024, 1024);
}

// Round 4
// 465.414 us; speedup vs baseline: 1.1070x; 1.0729x over previous
//
#include <hip/hip_runtime.h>
#include <hip/hip_bf16.h>
#include <stdint.h>

typedef __attribute__((ext_vector_type(8))) short short8;
typedef __attribute__((ext_vector_type(4))) short bf4;
typedef __attribute__((ext_vector_type(4))) float f32x4;

#define B_ 2
#define N1 2048
#define N2 256
#define NT 2304
#define D_ 1024
#define H_ 16
#define HD 64
// attention scale folded into Q: hd^-0.5 * log2(e)
#define QSCALE 0.18033688011112042f

static __device__ __forceinline__ float bf2f(short s){
  union { unsigned int u; float f; } u;
  u.u = ((unsigned int)(unsigned short)s) << 16;
  return u.f;
}
// round-to-nearest-even f32 -> bf16 (finite inputs)
static __device__ __forceinline__ short f2bf(float f){
  union { float f; unsigned int u; } v; v.f = f;
  unsigned int u = v.u;
  unsigned int lsb = (u >> 16) & 1u;
  u += 0x7fffu + lsb;
  return (short)(u >> 16);
}
static __device__ __forceinline__ unsigned int pack2(short a, short b){
  return (unsigned int)(unsigned short)a | (((unsigned int)(unsigned short)b) << 16);
}

static __device__ __forceinline__ float fexp2(float x){
#if __has_builtin(__builtin_amdgcn_exp2f)
  return __builtin_amdgcn_exp2f(x);
#else
  return exp2f(x);
#endif
}

static __device__ __forceinline__ void gload16(const void* g, void* l){
  __builtin_amdgcn_global_load_lds(
      (const __attribute__((address_space(1))) void*)g,
      (__attribute__((address_space(3))) void*)l, 16, 0, 0);
}

// ---------------- fp32 -> bf16 convert ----------------
__global__ __launch_bounds__(256) void k_cvt_bf16(const float* __restrict__ in,
                                                  short* __restrict__ out, int n){
  int i = (blockIdx.x * 256 + threadIdx.x) * 8;
  if (i >= n) return;
  float4 a = *(const float4*)(in + i);
  float4 b = *(const float4*)(in + i + 4);
  short8 o;
  o[0]=f2bf(a.x); o[1]=f2bf(a.y); o[2]=f2bf(a.z); o[3]=f2bf(a.w);
  o[4]=f2bf(b.x); o[5]=f2bf(b.y); o[6]=f2bf(b.z); o[7]=f2bf(b.w);
  *(short8*)(out + i) = o;
}

// ---------------- W (K x N, f32) -> Wt (N x K, bf16) ----------------
__global__ __launch_bounds__(256) void k_transpose_w(const float* __restrict__ W,
                                                     short* __restrict__ Wt,
                                                     int K, int N){
  __shared__ float tl[64][65];
  const int n0 = blockIdx.x * 64, k0 = blockIdx.y * 64;
  const int t = threadIdx.x, r = t >> 2, c = (t & 3) * 16;
  const float* src = W + (size_t)(k0 + r) * N + n0 + c;
  #pragma unroll
  for (int i = 0; i < 16; i += 4){
    float4 v = *(const float4*)(src + i);
    tl[r][c+i] = v.x; tl[r][c+i+1] = v.y; tl[r][c+i+2] = v.z; tl[r][c+i+3] = v.w;
  }
  __syncthreads();
  short8 o0, o1;
  #pragma unroll
  for (int i = 0; i < 8; i++) o0[i] = f2bf(tl[c+i][r]);
  #pragma unroll
  for (int i = 0; i < 8; i++) o1[i] = f2bf(tl[c+8+i][r]);
  short* dst = Wt + (size_t)(n0 + r) * K + k0 + c;
  *(short8*)(dst)     = o0;
  *(short8*)(dst + 8) = o1;
}

// ---------------- GEMM: C[M,N] = A[M,K] * Bt[N,K]^T + bias ----------------
template<int OUT_BF16>
__global__ __launch_bounds__(256) void k_gemm_bt(const short* __restrict__ A,
                                                 const short* __restrict__ Bt,
                                                 const float* __restrict__ bias,
                                                 void* __restrict__ Cp,
                                                 int M, int N, int K){
  __shared__ __align__(16) short As[128*32];
  __shared__ __align__(16) short Bs[128*32];
  const int t = threadIdx.x;
  const int w = t >> 6, l = t & 63;
  const int lc = l & 15, g = l >> 4;
  const int tm = blockIdx.y * 128, tn = blockIdx.x * 128;
  const int wm = (w >> 1) * 64, wn = (w & 1) * 64;

  const int r0 = w*32 + (l >> 2);
  const int r1 = r0 + 16;
  const int cb = (l & 3) * 16;

  const char* Ag0 = (const char*)(A + (size_t)(tm + r0) * K) + cb;
  const char* Ag1 = (const char*)(A + (size_t)(tm + r1) * K) + cb;
  const char* Bg0 = (const char*)(Bt + (size_t)(tn + r0) * K) + cb;
  const char* Bg1 = (const char*)(Bt + (size_t)(tn + r1) * K) + cb;
  char* Al0 = (char*)As + (w*2  )*1024;
  char* Al1 = (char*)As + (w*2+1)*1024;
  char* Bl0 = (char*)Bs + (w*2  )*1024;
  char* Bl1 = (char*)Bs + (w*2+1)*1024;

  f32x4 acc[4][4];
  #pragma unroll
  for (int m=0;m<4;m++){
    #pragma unroll
    for (int n=0;n<4;n++){ acc[m][n][0]=0.f; acc[m][n][1]=0.f; acc[m][n][2]=0.f; acc[m][n][3]=0.f; }
  }

  for (int k0 = 0; k0 < K; k0 += 32){
    const int kb = k0 * 2;
    gload16(Ag0 + kb, Al0);
    gload16(Ag1 + kb, Al1);
    gload16(Bg0 + kb, Bl0);
    gload16(Bg1 + kb, Bl1);
    __syncthreads();
    short8 af[4], bfr[4];
    #pragma unroll
    for (int m=0;m<4;m++) af[m]  = *(const short8*)(As + (wm + m*16 + lc)*32 + g*8);
    #pragma unroll
    for (int n=0;n<4;n++) bfr[n] = *(const short8*)(Bs + (wn + n*16 + lc)*32 + g*8);
    #pragma unroll
    for (int m=0;m<4;m++){
      #pragma unroll
      for (int n=0;n<4;n++)
        acc[m][n] = __builtin_amdgcn_mfma_f32_16x16x32_bf16(af[m], bfr[n], acc[m][n], 0, 0, 0);
    }
    __syncthreads();
  }

  #pragma unroll
  for (int n=0;n<4;n++){
    const int col = tn + wn + n*16 + lc;
    const float bv = bias[col];
    #pragma unroll
    for (int m=0;m<4;m++){
      const int row = tm + wm + m*16 + g*4;
      #pragma unroll
      for (int r=0;r<4;r++){
        float v = acc[m][n][r] + bv;
        if (OUT_BF16) ((short*)Cp)[(size_t)(row + r)*N + col] = f2bf(v);
        else          ((float*)Cp)[(size_t)(row + r)*N + col] = v;
      }
    }
  }
}

// ---------------- per-head LN (+ optional RoPE), split QKV ----------------
__global__ __launch_bounds__(256) void k_lnrope(const short* __restrict__ qkv,
    const float* __restrict__ qw, const float* __restrict__ qb,
    const float* __restrict__ kw, const float* __restrict__ kb,
    const float* __restrict__ fcos, const float* __restrict__ fsin,
    short* __restrict__ Qo, short* __restrict__ Ko, short* __restrict__ Vo,
    int Nseq, int posoff, int use_rope){
  const int wv = (blockIdx.x * 256 + threadIdx.x) >> 6;
  const int l = threadIdx.x & 63;
  const int h = wv % H_;
  const int n = (wv / H_) % Nseq;
  const int b = wv / (H_ * Nseq);
  const size_t ibase = ((size_t)(b * Nseq + n)) * 3072 + h * 64 + l;
  float q = bf2f(qkv[ibase]);
  float k = bf2f(qkv[ibase + 1024]);
  short v = qkv[ibase + 2048];

  float mu = q;
  #pragma unroll
  for (int mk = 1; mk < 64; mk <<= 1) mu += __shfl_xor(mu, mk, 64);
  mu *= (1.f/64.f);
  float dq = q - mu;
  float var = dq * dq;
  #pragma unroll
  for (int mk = 1; mk < 64; mk <<= 1) var += __shfl_xor(var, mk, 64);
  var *= (1.f/64.f);
  float qn = dq * rsqrtf(var + 1e-5f) * qw[l] + qb[l];

  float muk = k;
  #pragma unroll
  for (int mk = 1; mk < 64; mk <<= 1) muk += __shfl_xor(muk, mk, 64);
  muk *= (1.f/64.f);
  float dk = k - muk;
  float vark = dk * dk;
  #pragma unroll
  for (int mk = 1; mk < 64; mk <<= 1) vark += __shfl_xor(vark, mk, 64);
  vark *= (1.f/64.f);
  float kn = dk * rsqrtf(vark + 1e-5f) * kw[l] + kb[l];

  if (use_rope){
    float cv = fcos[(size_t)n * 32 + (l >> 1)];
    float sv = fsin[(size_t)n * 32 + (l >> 1)];
    float qp = __shfl_xor(qn, 1, 64);
    float kp = __shfl_xor(kn, 1, 64);
    qn = (l & 1) ? (qp * sv + qn * cv) : (qn * cv - qp * sv);
    kn = (l & 1) ? (kp * sv + kn * cv) : (kn * cv - kp * sv);
  }
  qn *= QSCALE;
  const size_t obase = ((size_t)(b * H_ + h) * NT + posoff + n) * HD + l;
  Qo[obase] = f2bf(qn);
  Ko[obase] = f2bf(kn);
  Vo[obase] = v;
}

// ---------------- V (B,H,NT,64) -> Vt (B,H,64,NT) ----------------
__global__ __launch_bounds__(256) void k_transpose_v(const short* __restrict__ V,
                                                     short* __restrict__ Vt){
  __shared__ short tl[64][72];
  const int blk = blockIdx.x;
  const int bh = blk / 36;
  const int n0 = (blk % 36) * 64;
  const int t = threadIdx.x, r = t >> 2, c = (t & 3) * 16;
  const short* src = V + ((size_t)bh * NT + n0 + r) * HD + c;
  short8 v0 = *(const short8*)(src);
  short8 v1 = *(const short8*)(src + 8);
  #pragma unroll
  for (int i=0;i<8;i++){ tl[r][c+i] = v0[i]; tl[r][c+8+i] = v1[i]; }
  __syncthreads();
  short8 o0, o1;
  #pragma unroll
  for (int i=0;i<8;i++){ o0[i] = tl[c+i][r]; o1[i] = tl[c+8+i][r]; }
  short* dst = Vt + ((size_t)bh * HD + r) * NT + n0 + c;
  *(short8*)dst       = o0;
  *(short8*)(dst + 8) = o1;
}

// ---------------- flash attention, fully swapped (S^T and O^T in regs) ----
// block = 4 waves over 32 q-rows: wave w: q-sub (w&1)*16, KV half (w>>1).
// QK^T as mfma(K,Q): lane (lc,g) holds S[q=lc][kv=16j+4g+r] -> softmax state
// (m,l) is lane-local for q-row lc (replicated across g).
// PV as mfma(V^T,P^T): oacc[jd][r] = O^T[d=16jd+4g+r][q=lc] -> rescale and
// normalize are lane-local too. P round-trips LDS (write [lc][16j+4g+r],
// read [lc][kk*32+g*8..]) exactly as the verified r2 kernel.
__global__ __launch_bounds__(256) void k_attn(const short* __restrict__ Q,
                                              const short* __restrict__ Kg,
                                              const short* __restrict__ Vt,
                                              short* __restrict__ o1,
                                              short* __restrict__ o2){
  __shared__ __align__(16) short Ps[4][16][72];
  __shared__ float Om[2][64][17];
  __shared__ float Ms[2][16], Ls[2][16];
  const int t = threadIdx.x, w = t >> 6, l = t & 63;
  const int lc = l & 15, g = l >> 4;
  const int h = w >> 1, qsub = w & 1;
  const int blk = blockIdx.x;
  const int bh = blk / 72, qt = blk % 72;
  const int b = bh >> 4, hh = bh & 15;
  const int q0 = qt * 32 + qsub * 16;
  const short* Qb = Q  + (size_t)bh * NT * HD;
  const short* Kb = Kg + (size_t)bh * NT * HD;
  const short* Vb = Vt + (size_t)bh * HD * NT;

  // Q fragment (B-operand): col q=lc, k-elems = head-dims g*8.. / +32
  short8 qf0 = *(const short8*)(Qb + (size_t)(q0 + lc) * HD + g*8);
  short8 qf1 = *(const short8*)(Qb + (size_t)(q0 + lc) * HD + g*8 + 32);

  float mcur = -1e30f, lcur = 0.f;
  f32x4 oacc[4];
  #pragma unroll
  for (int j=0;j<4;j++){ oacc[j][0]=0.f; oacc[j][1]=0.f; oacc[j][2]=0.f; oacc[j][3]=0.f; }

  const int kvbase = h * 1152;
  // prologue: K fragments for tile 0
  short8 kc0[4], kc1[4];
  #pragma unroll
  for (int j=0;j<4;j++){
    const short* kp = Kb + (size_t)(kvbase + j*16 + lc) * HD + g*8;
    kc0[j] = *(const short8*)(kp);
    kc1[j] = *(const short8*)(kp + 32);
  }

  for (int ti = 0; ti < 18; ++ti){
    const int kv0 = kvbase + ti * 64;
    // prefetch next tile's K fragments (dup of current on last iter; unused)
    const int kvn = kv0 + ((ti < 17) ? 64 : 0);
    short8 kn0[4], kn1[4];
    #pragma unroll
    for (int j=0;j<4;j++){
      const short* kp = Kb + (size_t)(kvn + j*16 + lc) * HD + g*8;
      kn0[j] = *(const short8*)(kp);
      kn1[j] = *(const short8*)(kp + 32);
    }
    // ---- S^T: s[j][r] = S[q=lc][kv = kv0 + 16j + 4g + r] ----
    f32x4 s[4];
    __builtin_amdgcn_s_setprio(1);
    #pragma unroll
    for (int j=0;j<4;j++){
      f32x4 a; a[0]=0.f; a[1]=0.f; a[2]=0.f; a[3]=0.f;
      a = __builtin_amdgcn_mfma_f32_16x16x32_bf16(kc0[j], qf0, a, 0, 0, 0);
      a = __builtin_amdgcn_mfma_f32_16x16x32_bf16(kc1[j], qf1, a, 0, 0, 0);
      s[j] = a;
    }
    __builtin_amdgcn_s_setprio(0);
    // ---- lane-local softmax for q-row lc ----
    float t0 = fmaxf(fmaxf(s[0][0], s[0][1]), fmaxf(s[0][2], s[0][3]));
    float t1 = fmaxf(fmaxf(s[1][0], s[1][1]), fmaxf(s[1][2], s[1][3]));
    float t2 = fmaxf(fmaxf(s[2][0], s[2][1]), fmaxf(s[2][2], s[2][3]));
    float t3 = fmaxf(fmaxf(s[3][0], s[3][1]), fmaxf(s[3][2], s[3][3]));
    float tmx = fmaxf(fmaxf(t0, t1), fmaxf(t2, t3));
    tmx = fmaxf(tmx, __shfl_xor(tmx, 16, 64));
    tmx = fmaxf(tmx, __shfl_xor(tmx, 32, 64));
    const float mn = fmaxf(mcur, tmx);
    const float fsc = fexp2(mcur - mn);
    mcur = mn;
    float p[4][4];
    #pragma unroll
    for (int j=0;j<4;j++){
      p[j][0] = fexp2(s[j][0] - mn);
      p[j][1] = fexp2(s[j][1] - mn);
      p[j][2] = fexp2(s[j][2] - mn);
      p[j][3] = fexp2(s[j][3] - mn);
    }
    float rs = ((p[0][0]+p[0][1])+(p[0][2]+p[0][3]))
             + ((p[1][0]+p[1][1])+(p[1][2]+p[1][3]))
             + ((p[2][0]+p[2][1])+(p[2][2]+p[2][3]))
             + ((p[3][0]+p[3][1])+(p[3][2]+p[3][3]));
    rs += __shfl_xor(rs, 16, 64);
    rs += __shfl_xor(rs, 32, 64);
    lcur = lcur * fsc + rs;
    // ---- rescale O^T accumulator: cols are q=lc -> lane-local factor ----
    #pragma unroll
    for (int j=0;j<4;j++){
      oacc[j][0] *= fsc; oacc[j][1] *= fsc; oacc[j][2] *= fsc; oacc[j][3] *= fsc;
    }
    // ---- P -> LDS: Ps[w][q=lc][kv], pairs at kv = 16j+4g+{0..3} ----
    #pragma unroll
    for (int j=0;j<4;j++){
      unsigned int* dst = (unsigned int*)&Ps[w][lc][16*j + 4*g];
      dst[0] = pack2(f2bf(p[j][0]), f2bf(p[j][1]));
      dst[1] = pack2(f2bf(p[j][2]), f2bf(p[j][3]));
    }
    // ---- PV swapped: oacc[jd] = mfma(V^T rows d, P^T cols q) ----
    #pragma unroll
    for (int kk=0;kk<2;kk++){
      short8 pa = *(const short8*)(&Ps[w][lc][kk*32 + g*8]);
      __builtin_amdgcn_s_setprio(1);
      #pragma unroll
      for (int jd=0;jd<4;jd++){
        short8 vb = *(const short8*)(Vb + (size_t)(lc + 16*jd) * NT + kv0 + kk*32 + g*8);
        oacc[jd] = __builtin_amdgcn_mfma_f32_16x16x32_bf16(vb, pa, oacc[jd], 0, 0, 0);
      }
      __builtin_amdgcn_s_setprio(0);
    }
    // advance prefetched K
    #pragma unroll
    for (int j=0;j<4;j++){ kc0[j] = kn0[j]; kc1[j] = kn1[j]; }
  }

  // ---- merge halves: all state lane-local (q=lc) ----
  if (h == 1){
    #pragma unroll
    for (int jd=0;jd<4;jd++){
      #pragma unroll
      for (int r=0;r<4;r++)
        Om[qsub][16*jd + 4*g + r][lc] = oacc[jd][r];
    }
    if (g == 0){ Ms[qsub][lc] = mcur; Ls[qsub][lc] = lcur; }
  }
  __syncthreads();
  if (h == 0){
    const float m1 = Ms[qsub][lc];
    const float l1v = Ls[qsub][lc];
    const float M = fmaxf(mcur, m1);
    const float fA = fexp2(mcur - M);
    const float fB = fexp2(m1 - M);
    const float inv = 1.0f / (lcur * fA + l1v * fB);
    const int qi = q0 + lc;
    short* obase = (qi < N1) ? (o1 + ((size_t)b * N1 + qi) * D_)
                             : (o2 + ((size_t)b * N2 + (qi - N1)) * D_);
    #pragma unroll
    for (int jd=0;jd<4;jd++){
      bf4 ov;
      #pragma unroll
      for (int r=0;r<4;r++){
        const float o1v = Om[qsub][16*jd + 4*g + r][lc];
        ov[r] = f2bf((oacc[jd][r] * fA + o1v * fB) * inv);
      }
      *(bf4*)(obase + hh*64 + 16*jd + 4*g) = ov;
    }
  }
}

extern "C" void kernel_launch(void* const* d_in, const int* in_sizes, int n_in,
                              void* d_out, int out_size, void* d_ws, size_t ws_size,
                              hipStream_t stream){
  const float* x    = (const float*)d_in[0];
  const float* c    = (const float*)d_in[1];
  const float* fc   = (const float*)d_in[2];
  const float* fs   = (const float*)d_in[3];
  const float* Wq1  = (const float*)d_in[4];
  const float* bq1  = (const float*)d_in[5];
  const float* Wq2  = (const float*)d_in[6];
  const float* bq2  = (const float*)d_in[7];
  const float* qn1w = (const float*)d_in[8];
  const float* qn1b = (const float*)d_in[9];
  const float* kn1w = (const float*)d_in[10];
  const float* kn1b = (const float*)d_in[11];
  const float* qn2w = (const float*)d_in[12];
  const float* qn2b = (const float*)d_in[13];
  const float* kn2w = (const float*)d_in[14];
  const float* kn2b = (const float*)d_in[15];
  const float* Wp1  = (const float*)d_in[16];
  const float* bp1  = (const float*)d_in[17];
  const float* Wp2  = (const float*)d_in[18];
  const float* bp2  = (const float*)d_in[19];
  float* out = (float*)d_out;

  char* ws = (char*)d_ws;
  short* xb   = (short*)(ws);                       // 8,388,608
  short* cb   = (short*)(ws + 8388608);             // 1,048,576
  short* Wt1  = (short*)(ws + 9437184);             // 6,291,456
  short* Wt2  = (short*)(ws + 15728640);            // 6,291,456
  short* Wtp1 = (short*)(ws + 22020096);            // 2,097,152
  short* Wtp2 = (short*)(ws + 24117248);            // 2,097,152
  short* qkv1 = (short*)(ws + 26214400);            // 25,165,824 (bf16 4096x3072)
  short* qkv2 = (short*)(ws + 51380224);            // 3,145,728
  short* Qb   = (short*)(ws + 54525952);            // 9,437,184
  short* Kb   = (short*)(ws + 63963136);            // 9,437,184
  short* Vb   = (short*)(ws + 73400320);            // 9,437,184  -> total 82,837,504
  // aliases into qkv1 region (qkv1 fully consumed by k_lnrope before these are written)
  short* o1   = (short*)(ws + 26214400);            // 8,388,608
  short* o2   = (short*)(ws + 26214400 + 8388608);  // 1,048,576
  short* Vtb  = (short*)(ws + 26214400 + 9437184);  // 9,437,184

  k_cvt_bf16<<<2048, 256, 0, stream>>>(x, xb, 4194304);
  k_cvt_bf16<<<256, 256, 0, stream>>>(c, cb, 524288);
  k_transpose_w<<<dim3(48,16), 256, 0, stream>>>(Wq1, Wt1, 1024, 3072);
  k_transpose_w<<<dim3(48,16), 256, 0, stream>>>(Wq2, Wt2, 1024, 3072);
  k_transpose_w<<<dim3(16,16), 256, 0, stream>>>(Wp1, Wtp1, 1024, 1024);
  k_transpose_w<<<dim3(16,16), 256, 0, stream>>>(Wp2, Wtp2, 1024, 1024);

  k_gemm_bt<1><<<dim3(24,32), 256, 0, stream>>>(xb, Wt1, bq1, qkv1, 4096, 3072, 1024);
  k_gemm_bt<1><<<dim3(24,4),  256, 0, stream>>>(cb, Wt2, bq2, qkv2,  512, 3072, 1024);

  k_lnrope<<<16384, 256, 0, stream>>>(qkv1, qn1w, qn1b, kn1w, kn1b, fc, fs, Qb, Kb, Vb, 2048, 0, 1);
  k_lnrope<<<2048,  256, 0, stream>>>(qkv2, qn2w, qn2b, kn2w, kn2b, fc, fs, Qb, Kb, Vb,  256, 2048, 0);

  k_transpose_v<<<1152, 256, 0, stream>>>(Vb, Vtb);
  k_attn<<<2304, 256, 0, stream>>>(Qb, Kb, Vtb, o1, o2);

  k_gemm_bt<0><<<dim3(8,32), 256, 0, stream>>>(o1, Wtp1, bp1, out,           4096, 1024, 1024);
  k_gemm_bt<0><<<dim3(8,4),  256, 0, stream>>>(o2, Wtp2, bp2, out + 4194304,  512, 1024, 1024);
}

// Round 6
// 273.074 us; speedup vs baseline: 1.8867x; 1.7044x over previous
//
#include <hip/hip_runtime.h>
#include <hip/hip_bf16.h>
#include <stdint.h>

typedef __attribute__((ext_vector_type(8))) short short8;
typedef __attribute__((ext_vector_type(4))) short bf4;
typedef __attribute__((ext_vector_type(4))) float f32x4;

#define B_ 2
#define N1 2048
#define N2 256
#define NT 2304
#define D_ 1024
#define H_ 16
#define HD 64
// attention scale folded into Q: hd^-0.5 * log2(e)
#define QSCALE 0.18033688011112042f

static __device__ __forceinline__ float bf2f(short s){
  union { unsigned int u; float f; } u;
  u.u = ((unsigned int)(unsigned short)s) << 16;
  return u.f;
}
// round-to-nearest-even f32 -> bf16 (finite inputs)
static __device__ __forceinline__ short f2bf(float f){
  union { float f; unsigned int u; } v; v.f = f;
  unsigned int u = v.u;
  unsigned int lsb = (u >> 16) & 1u;
  u += 0x7fffu + lsb;
  return (short)(u >> 16);
}
static __device__ __forceinline__ unsigned int pack2(short a, short b){
  return (unsigned int)(unsigned short)a | (((unsigned int)(unsigned short)b) << 16);
}

static __device__ __forceinline__ float fexp2(float x){
#if __has_builtin(__builtin_amdgcn_exp2f)
  return __builtin_amdgcn_exp2f(x);
#else
  return exp2f(x);
#endif
}

static __device__ __forceinline__ void gload16(const void* g, void* l){
  __builtin_amdgcn_global_load_lds(
      (const __attribute__((address_space(1))) void*)g,
      (__attribute__((address_space(3))) void*)l, 16, 0, 0);
}

// ---------------- fp32 -> bf16 convert ----------------
__global__ __launch_bounds__(256) void k_cvt_bf16(const float* __restrict__ in,
                                                  short* __restrict__ out, int n){
  int i = (blockIdx.x * 256 + threadIdx.x) * 8;
  if (i >= n) return;
  float4 a = *(const float4*)(in + i);
  float4 b = *(const float4*)(in + i + 4);
  short8 o;
  o[0]=f2bf(a.x); o[1]=f2bf(a.y); o[2]=f2bf(a.z); o[3]=f2bf(a.w);
  o[4]=f2bf(b.x); o[5]=f2bf(b.y); o[6]=f2bf(b.z); o[7]=f2bf(b.w);
  *(short8*)(out + i) = o;
}

// ---------------- W (K x N, f32) -> Wt (N x K, bf16) ----------------
__global__ __launch_bounds__(256) void k_transpose_w(const float* __restrict__ W,
                                                     short* __restrict__ Wt,
                                                     int K, int N){
  __shared__ float tl[64][65];
  const int n0 = blockIdx.x * 64, k0 = blockIdx.y * 64;
  const int t = threadIdx.x, r = t >> 2, c = (t & 3) * 16;
  const float* src = W + (size_t)(k0 + r) * N + n0 + c;
  #pragma unroll
  for (int i = 0; i < 16; i += 4){
    float4 v = *(const float4*)(src + i);
    tl[r][c+i] = v.x; tl[r][c+i+1] = v.y; tl[r][c+i+2] = v.z; tl[r][c+i+3] = v.w;
  }
  __syncthreads();
  short8 o0, o1;
  #pragma unroll
  for (int i = 0; i < 8; i++) o0[i] = f2bf(tl[c+i][r]);
  #pragma unroll
  for (int i = 0; i < 8; i++) o1[i] = f2bf(tl[c+8+i][r]);
  short* dst = Wt + (size_t)(n0 + r) * K + k0 + c;
  *(short8*)(dst)     = o0;
  *(short8*)(dst + 8) = o1;
}

// ---------------- GEMM: C[M,N] = A[M,K] * Bt[N,K]^T + bias ----------------
template<int OUT_BF16>
__global__ __launch_bounds__(256) void k_gemm_bt(const short* __restrict__ A,
                                                 const short* __restrict__ Bt,
                                                 const float* __restrict__ bias,
                                                 void* __restrict__ Cp,
                                                 int M, int N, int K){
  __shared__ __align__(16) short As[128*32];
  __shared__ __align__(16) short Bs[128*32];
  const int t = threadIdx.x;
  const int w = t >> 6, l = t & 63;
  const int lc = l & 15, g = l >> 4;
  const int tm = blockIdx.y * 128, tn = blockIdx.x * 128;
  const int wm = (w >> 1) * 64, wn = (w & 1) * 64;

  const int r0 = w*32 + (l >> 2);
  const int r1 = r0 + 16;
  const int cb = (l & 3) * 16;

  const char* Ag0 = (const char*)(A + (size_t)(tm + r0) * K) + cb;
  const char* Ag1 = (const char*)(A + (size_t)(tm + r1) * K) + cb;
  const char* Bg0 = (const char*)(Bt + (size_t)(tn + r0) * K) + cb;
  const char* Bg1 = (const char*)(Bt + (size_t)(tn + r1) * K) + cb;
  char* Al0 = (char*)As + (w*2  )*1024;
  char* Al1 = (char*)As + (w*2+1)*1024;
  char* Bl0 = (char*)Bs + (w*2  )*1024;
  char* Bl1 = (char*)Bs + (w*2+1)*1024;

  f32x4 acc[4][4];
  #pragma unroll
  for (int m=0;m<4;m++){
    #pragma unroll
    for (int n=0;n<4;n++){ acc[m][n][0]=0.f; acc[m][n][1]=0.f; acc[m][n][2]=0.f; acc[m][n][3]=0.f; }
  }

  for (int k0 = 0; k0 < K; k0 += 32){
    const int kb = k0 * 2;
    gload16(Ag0 + kb, Al0);
    gload16(Ag1 + kb, Al1);
    gload16(Bg0 + kb, Bl0);
    gload16(Bg1 + kb, Bl1);
    __syncthreads();
    short8 af[4], bfr[4];
    #pragma unroll
    for (int m=0;m<4;m++) af[m]  = *(const short8*)(As + (wm + m*16 + lc)*32 + g*8);
    #pragma unroll
    for (int n=0;n<4;n++) bfr[n] = *(const short8*)(Bs + (wn + n*16 + lc)*32 + g*8);
    #pragma unroll
    for (int m=0;m<4;m++){
      #pragma unroll
      for (int n=0;n<4;n++)
        acc[m][n] = __builtin_amdgcn_mfma_f32_16x16x32_bf16(af[m], bfr[n], acc[m][n], 0, 0, 0);
    }
    __syncthreads();
  }

  #pragma unroll
  for (int n=0;n<4;n++){
    const int col = tn + wn + n*16 + lc;
    const float bv = bias[col];
    #pragma unroll
    for (int m=0;m<4;m++){
      const int row = tm + wm + m*16 + g*4;
      #pragma unroll
      for (int r=0;r<4;r++){
        float v = acc[m][n][r] + bv;
        if (OUT_BF16) ((short*)Cp)[(size_t)(row + r)*N + col] = f2bf(v);
        else          ((float*)Cp)[(size_t)(row + r)*N + col] = v;
      }
    }
  }
}

// ---------------- per-head LN (+ optional RoPE), split QKV ----------------
__global__ __launch_bounds__(256) void k_lnrope(const short* __restrict__ qkv,
    const float* __restrict__ qw, const float* __restrict__ qb,
    const float* __restrict__ kw, const float* __restrict__ kb,
    const float* __restrict__ fcos, const float* __restrict__ fsin,
    short* __restrict__ Qo, short* __restrict__ Ko, short* __restrict__ Vo,
    int Nseq, int posoff, int use_rope){
  const int wv = (blockIdx.x * 256 + threadIdx.x) >> 6;
  const int l = threadIdx.x & 63;
  const int h = wv % H_;
  const int n = (wv / H_) % Nseq;
  const int b = wv / (H_ * Nseq);
  const size_t ibase = ((size_t)(b * Nseq + n)) * 3072 + h * 64 + l;
  float q = bf2f(qkv[ibase]);
  float k = bf2f(qkv[ibase + 1024]);
  short v = qkv[ibase + 2048];

  float mu = q;
  #pragma unroll
  for (int mk = 1; mk < 64; mk <<= 1) mu += __shfl_xor(mu, mk, 64);
  mu *= (1.f/64.f);
  float dq = q - mu;
  float var = dq * dq;
  #pragma unroll
  for (int mk = 1; mk < 64; mk <<= 1) var += __shfl_xor(var, mk, 64);
  var *= (1.f/64.f);
  float qn = dq * rsqrtf(var + 1e-5f) * qw[l] + qb[l];

  float muk = k;
  #pragma unroll
  for (int mk = 1; mk < 64; mk <<= 1) muk += __shfl_xor(muk, mk, 64);
  muk *= (1.f/64.f);
  float dk = k - muk;
  float vark = dk * dk;
  #pragma unroll
  for (int mk = 1; mk < 64; mk <<= 1) vark += __shfl_xor(vark, mk, 64);
  vark *= (1.f/64.f);
  float kn = dk * rsqrtf(vark + 1e-5f) * kw[l] + kb[l];

  if (use_rope){
    float cv = fcos[(size_t)n * 32 + (l >> 1)];
    float sv = fsin[(size_t)n * 32 + (l >> 1)];
    float qp = __shfl_xor(qn, 1, 64);
    float kp = __shfl_xor(kn, 1, 64);
    qn = (l & 1) ? (qp * sv + qn * cv) : (qn * cv - qp * sv);
    kn = (l & 1) ? (kp * sv + kn * cv) : (kn * cv - kp * sv);
  }
  qn *= QSCALE;
  const size_t obase = ((size_t)(b * H_ + h) * NT + posoff + n) * HD + l;
  Qo[obase] = f2bf(qn);
  Ko[obase] = f2bf(kn);
  Vo[obase] = v;
}

// ---------------- V (B,H,NT,64) -> Vt (B,H,64,NT) ----------------
__global__ __launch_bounds__(256) void k_transpose_v(const short* __restrict__ V,
                                                     short* __restrict__ Vt){
  __shared__ short tl[64][72];
  const int blk = blockIdx.x;
  const int bh = blk / 36;
  const int n0 = (blk % 36) * 64;
  const int t = threadIdx.x, r = t >> 2, c = (t & 3) * 16;
  const short* src = V + ((size_t)bh * NT + n0 + r) * HD + c;
  short8 v0 = *(const short8*)(src);
  short8 v1 = *(const short8*)(src + 8);
  #pragma unroll
  for (int i=0;i<8;i++){ tl[r][c+i] = v0[i]; tl[r][c+8+i] = v1[i]; }
  __syncthreads();
  short8 o0, o1;
  #pragma unroll
  for (int i=0;i<8;i++){ o0[i] = tl[c+i][r]; o1[i] = tl[c+8+i][r]; }
  short* dst = Vt + ((size_t)bh * HD + r) * NT + n0 + c;
  *(short8*)dst       = o0;
  *(short8*)(dst + 8) = o1;
}

// ---------------- flash attention: block-cooperative LDS-staged K/V -------
// 1152 blocks = 32 bh x 36 q-tiles, XCD-chunked (blk%8 = XCD; each XCD owns
// 4 bh -> K/V set 2.4MB, L2-resident). 4 waves share the 64-q-row tile
// (wave w: q0 = qt*64 + w*16) and iterate all 36 KV tiles of 64.
// K and V^T tiles are double-buffered in pad-72 LDS; each thread stages
// 32B of K and 32B of V per tile (full 8KB tile per buffer). Next tile's
// global loads issue before compute (latency hidden), one barrier per tile.
// Compute = round-4-verified swapped QK^T / lane-local softmax / swapped PV.
__global__ __launch_bounds__(256) void k_attn(const short* __restrict__ Q,
                                              const short* __restrict__ Kg,
                                              const short* __restrict__ Vt,
                                              short* __restrict__ o1,
                                              short* __restrict__ o2){
  __shared__ __align__(16) short Kl[2][64][72];
  __shared__ __align__(16) short Vl[2][64][72];
  __shared__ __align__(16) short Ps[4][16][72];
  const int t = threadIdx.x, w = t >> 6, l = t & 63;
  const int lc = l & 15, g = l >> 4;
  const int blk = blockIdx.x;
  const int c = blk & 7, i = blk >> 3;      // 1152 = 8 * 144
  const int bh = c * 4 + (i / 36);          // 4 bh per XCD-chunk
  const int qt = i % 36;
  const int b = bh >> 4, hh = bh & 15;
  const int q0 = qt * 64 + w * 16;
  const short* Qb = Q  + (size_t)bh * NT * HD;
  const short* Kb = Kg + (size_t)bh * NT * HD;
  const short* Vb = Vt + (size_t)bh * HD * NT;

  // Q fragment (B-operand): col q=lc, k-elems = head-dims g*8.. / +32
  short8 qf0 = *(const short8*)(Qb + (size_t)(q0 + lc) * HD + g*8);
  short8 qf1 = *(const short8*)(Qb + (size_t)(q0 + lc) * HD + g*8 + 32);

  // staging role: row sr, 32B chunk at short-offset sc (16 shorts/thread)
  const int sr = t >> 2, sc = (t & 3) * 16;
  const short* Kgp = Kb + (size_t)sr * HD + sc;   // + ti*64*HD per tile
  const short* Vgp = Vb + (size_t)sr * NT + sc;   // + ti*64     per tile

  float mcur = -1e30f, lcur = 0.f;
  f32x4 oacc[4];
  #pragma unroll
  for (int j=0;j<4;j++){ oacc[j][0]=0.f; oacc[j][1]=0.f; oacc[j][2]=0.f; oacc[j][3]=0.f; }

  // prologue: stage tile 0 into buffer 0 (full 64x64: two short8 per thread)
  {
    short8 k0 = *(const short8*)(Kgp);
    short8 k1 = *(const short8*)(Kgp + 8);
    short8 v0 = *(const short8*)(Vgp);
    short8 v1 = *(const short8*)(Vgp + 8);
    *(short8*)&Kl[0][sr][sc]     = k0;
    *(short8*)&Kl[0][sr][sc + 8] = k1;
    *(short8*)&Vl[0][sr][sc]     = v0;
    *(short8*)&Vl[0][sr][sc + 8] = v1;
  }
  __syncthreads();

  for (int ti = 0; ti < 36; ++ti){
    const int cur = ti & 1;
    // issue next tile's global loads early (hide latency under compute)
    short8 kn0, kn1, vn0, vn1;
    if (ti < 35){
      const short* kp = Kgp + (size_t)(ti + 1) * 64 * HD;
      const short* vp = Vgp + (ti + 1) * 64;
      kn0 = *(const short8*)(kp);
      kn1 = *(const short8*)(kp + 8);
      vn0 = *(const short8*)(vp);
      vn1 = *(const short8*)(vp + 8);
    }
    // ---- S^T: s[j][r] = S[q=lc][kv = ti*64 + 16j + 4g + r] ----
    f32x4 s[4];
    __builtin_amdgcn_s_setprio(1);
    #pragma unroll
    for (int j=0;j<4;j++){
      const short* kp = &Kl[cur][j*16 + lc][g*8];
      short8 k0 = *(const short8*)(kp);
      short8 k1 = *(const short8*)(kp + 32);
      f32x4 a; a[0]=0.f; a[1]=0.f; a[2]=0.f; a[3]=0.f;
      a = __builtin_amdgcn_mfma_f32_16x16x32_bf16(k0, qf0, a, 0, 0, 0);
      a = __builtin_amdgcn_mfma_f32_16x16x32_bf16(k1, qf1, a, 0, 0, 0);
      s[j] = a;
    }
    __builtin_amdgcn_s_setprio(0);
    // ---- lane-local softmax for q-row lc ----
    float t0 = fmaxf(fmaxf(s[0][0], s[0][1]), fmaxf(s[0][2], s[0][3]));
    float t1 = fmaxf(fmaxf(s[1][0], s[1][1]), fmaxf(s[1][2], s[1][3]));
    float t2 = fmaxf(fmaxf(s[2][0], s[2][1]), fmaxf(s[2][2], s[2][3]));
    float t3 = fmaxf(fmaxf(s[3][0], s[3][1]), fmaxf(s[3][2], s[3][3]));
    float tmx = fmaxf(fmaxf(t0, t1), fmaxf(t2, t3));
    tmx = fmaxf(tmx, __shfl_xor(tmx, 16, 64));
    tmx = fmaxf(tmx, __shfl_xor(tmx, 32, 64));
    const float mn = fmaxf(mcur, tmx);
    const float fsc = fexp2(mcur - mn);
    mcur = mn;
    float p[4][4];
    #pragma unroll
    for (int j=0;j<4;j++){
      p[j][0] = fexp2(s[j][0] - mn);
      p[j][1] = fexp2(s[j][1] - mn);
      p[j][2] = fexp2(s[j][2] - mn);
      p[j][3] = fexp2(s[j][3] - mn);
    }
    float rs = ((p[0][0]+p[0][1])+(p[0][2]+p[0][3]))
             + ((p[1][0]+p[1][1])+(p[1][2]+p[1][3]))
             + ((p[2][0]+p[2][1])+(p[2][2]+p[2][3]))
             + ((p[3][0]+p[3][1])+(p[3][2]+p[3][3]));
    rs += __shfl_xor(rs, 16, 64);
    rs += __shfl_xor(rs, 32, 64);
    lcur = lcur * fsc + rs;
    // ---- rescale O^T accumulator (cols q=lc -> lane-local) ----
    #pragma unroll
    for (int j=0;j<4;j++){
      oacc[j][0] *= fsc; oacc[j][1] *= fsc; oacc[j][2] *= fsc; oacc[j][3] *= fsc;
    }
    // ---- P -> LDS: Ps[w][q=lc][kv], pairs at kv = 16j+4g+{0..3} ----
    #pragma unroll
    for (int j=0;j<4;j++){
      unsigned int* dst = (unsigned int*)&Ps[w][lc][16*j + 4*g];
      dst[0] = pack2(f2bf(p[j][0]), f2bf(p[j][1]));
      dst[1] = pack2(f2bf(p[j][2]), f2bf(p[j][3]));
    }
    // ---- PV swapped: oacc[jd] = mfma(V^T rows d, P^T cols q) ----
    #pragma unroll
    for (int kk=0;kk<2;kk++){
      short8 pa = *(const short8*)(&Ps[w][lc][kk*32 + g*8]);
      __builtin_amdgcn_s_setprio(1);
      #pragma unroll
      for (int jd=0;jd<4;jd++){
        short8 vb = *(const short8*)(&Vl[cur][lc + 16*jd][kk*32 + g*8]);
        oacc[jd] = __builtin_amdgcn_mfma_f32_16x16x32_bf16(vb, pa, oacc[jd], 0, 0, 0);
      }
      __builtin_amdgcn_s_setprio(0);
    }
    // ---- write next tile into the other buffer, then sync ----
    if (ti < 35){
      *(short8*)&Kl[cur ^ 1][sr][sc]     = kn0;
      *(short8*)&Kl[cur ^ 1][sr][sc + 8] = kn1;
      *(short8*)&Vl[cur ^ 1][sr][sc]     = vn0;
      *(short8*)&Vl[cur ^ 1][sr][sc + 8] = vn1;
    }
    __syncthreads();
  }

  // ---- epilogue: normalize (lane-local) and write ----
  const float inv = 1.0f / lcur;
  const int qi = q0 + lc;
  short* obase = (qi < N1) ? (o1 + ((size_t)b * N1 + qi) * D_)
                           : (o2 + ((size_t)b * N2 + (qi - N1)) * D_);
  #pragma unroll
  for (int jd=0;jd<4;jd++){
    bf4 ov;
    #pragma unroll
    for (int r=0;r<4;r++) ov[r] = f2bf(oacc[jd][r] * inv);
    *(bf4*)(obase + hh*64 + 16*jd + 4*g) = ov;
  }
}

extern "C" void kernel_launch(void* const* d_in, const int* in_sizes, int n_in,
                              void* d_out, int out_size, void* d_ws, size_t ws_size,
                              hipStream_t stream){
  const float* x    = (const float*)d_in[0];
  const float* c    = (const float*)d_in[1];
  const float* fc   = (const float*)d_in[2];
  const float* fs   = (const float*)d_in[3];
  const float* Wq1  = (const float*)d_in[4];
  const float* bq1  = (const float*)d_in[5];
  const float* Wq2  = (const float*)d_in[6];
  const float* bq2  = (const float*)d_in[7];
  const float* qn1w = (const float*)d_in[8];
  const float* qn1b = (const float*)d_in[9];
  const float* kn1w = (const float*)d_in[10];
  const float* kn1b = (const float*)d_in[11];
  const float* qn2w = (const float*)d_in[12];
  const float* qn2b = (const float*)d_in[13];
  const float* kn2w = (const float*)d_in[14];
  const float* kn2b = (const float*)d_in[15];
  const float* Wp1  = (const float*)d_in[16];
  const float* bp1  = (const float*)d_in[17];
  const float* Wp2  = (const float*)d_in[18];
  const float* bp2  = (const float*)d_in[19];
  float* out = (float*)d_out;

  char* ws = (char*)d_ws;
  short* xb   = (short*)(ws);                       // 8,388,608
  short* cb   = (short*)(ws + 8388608);             // 1,048,576
  short* Wt1  = (short*)(ws + 9437184);             // 6,291,456
  short* Wt2  = (short*)(ws + 15728640);            // 6,291,456
  short* Wtp1 = (short*)(ws + 22020096);            // 2,097,152
  short* Wtp2 = (short*)(ws + 24117248);            // 2,097,152
  short* qkv1 = (short*)(ws + 26214400);            // 25,165,824 (bf16 4096x3072)
  short* qkv2 = (short*)(ws + 51380224);            // 3,145,728
  short* Qb   = (short*)(ws + 54525952);            // 9,437,184
  short* Kb   = (short*)(ws + 63963136);            // 9,437,184
  short* Vb   = (short*)(ws + 73400320);            // 9,437,184  -> total 82,837,504
  // aliases into qkv1 region (qkv1 fully consumed by k_lnrope before these are written)
  short* o1   = (short*)(ws + 26214400);            // 8,388,608
  short* o2   = (short*)(ws + 26214400 + 8388608);  // 1,048,576
  short* Vtb  = (short*)(ws + 26214400 + 9437184);  // 9,437,184

  k_cvt_bf16<<<2048, 256, 0, stream>>>(x, xb, 4194304);
  k_cvt_bf16<<<256, 256, 0, stream>>>(c, cb, 524288);
  k_transpose_w<<<dim3(48,16), 256, 0, stream>>>(Wq1, Wt1, 1024, 3072);
  k_transpose_w<<<dim3(48,16), 256, 0, stream>>>(Wq2, Wt2, 1024, 3072);
  k_transpose_w<<<dim3(16,16), 256, 0, stream>>>(Wp1, Wtp1, 1024, 1024);
  k_transpose_w<<<dim3(16,16), 256, 0, stream>>>(Wp2, Wtp2, 1024, 1024);

  k_gemm_bt<1><<<dim3(24,32), 256, 0, stream>>>(xb, Wt1, bq1, qkv1, 4096, 3072, 1024);
  k_gemm_bt<1><<<dim3(24,4),  256, 0, stream>>>(cb, Wt2, bq2, qkv2,  512, 3072, 1024);

  k_lnrope<<<16384, 256, 0, stream>>>(qkv1, qn1w, qn1b, kn1w, kn1b, fc, fs, Qb, Kb, Vb, 2048, 0, 1);
  k_lnrope<<<2048,  256, 0, stream>>>(qkv2, qn2w, qn2b, kn2w, kn2b, fc, fs, Qb, Kb, Vb,  256, 2048, 0);

  k_transpose_v<<<1152, 256, 0, stream>>>(Vb, Vtb);
  k_attn<<<1152, 256, 0, stream>>>(Qb, Kb, Vtb, o1, o2);

  k_gemm_bt<0><<<dim3(8,32), 256, 0, stream>>>(o1, Wtp1, bp1, out,           4096, 1024, 1024);
  k_gemm_bt<0><<<dim3(8,4),  256, 0, stream>>>(o2, Wtp2, bp2, out + 4194304,  512, 1024, 1024);
}